// Round 8
// baseline (499.740 us; speedup 1.0000x reference)
//
#include <hip/hip_runtime.h>
#include <cstddef>

// ---- problem constants ----
constexpr int kN  = 16;
constexpr int kI  = 128;
constexpr int kHW = 24;
constexpr int kQ  = 576;    // 24*24
constexpr int kD  = 484;    // 22*22
constexpr int kDP = 512;    // padded d
constexpr int kPP = 676;    // 26*26 padded

// K-tiling
constexpr int kKTQKV = 144;   // K = 4608 (2 src * 9 tap * 256 ic)
constexpr int kKTG   = 152;   // K = 4864 (4608 + 256 from a16)
constexpr int kKTO   = 8;     // K = 256

// ---- workspace layout (element offsets into _Float16*) ----
constexpr size_t H_XPAD   = 0;                          // [16][26][26][256] NHWC
constexpr size_t H_HPAD   = 2768896;                    // [16][26][26][256] NHWC
constexpr size_t H_APQKV  = 5537792;                    // 6 mt * 144 kt * 4096
constexpr size_t H_APG    = 9076736;                    // 8 mt * 152 kt * 4096
constexpr size_t H_APO    = 14057472;                   // 2 mt * 8 kt * 4096
constexpr size_t H_A16    = 14123008;                   // [16][576][256]
constexpr size_t H_H16    = 16482304;                   // [16][576][256]
constexpr size_t H_Q16C   = 18841600;                   // [16][256][576]
constexpr size_t H_KT16   = 21200896;                   // [128 head][512 d][32 c]
constexpr size_t H_VC16   = 23298048;                   // [128 head][32 c][512 d]

using half8    = __attribute__((ext_vector_type(8))) _Float16;
using floatx16 = __attribute__((ext_vector_type(16))) float;

__device__ __forceinline__ float sigm(float x) { return 1.0f / (1.0f + __expf(-x)); }
__device__ __forceinline__ float tanh_f(float x) {
    float e = __expf(2.0f * fabsf(x));
    float r = 1.0f - 2.0f / (e + 1.0f);
    return copysignf(r, x);
}
__device__ __forceinline__ half8 LD8(const _Float16* p) { return *(const half8*)p; }
__device__ __forceinline__ void ST8(_Float16* p, half8 v) { *(half8*)p = v; }

// ---------------- weight packing ----------------
// Apack layout: [mt][kt][kk(2)][hl(2)][row(128)][j(8)], 4096 halves per (mt,kt).
// K-order (im2col GEMMs): k = src*2304 + tap*256 + ic.

// qkv pack: M=768 (mt 0-1 q, 2-3 k, 4-5 v).
__global__ void pack_qkv_kernel(const float* __restrict__ wq_x, const float* __restrict__ wq_h,
                                const float* __restrict__ wk_x, const float* __restrict__ wk_h,
                                const float* __restrict__ wv_x, const float* __restrict__ wv_h,
                                _Float16* __restrict__ dst) {
    int pidx = blockIdx.x * 256 + threadIdx.x;
    int j = pidx & 7, row = (pidx >> 3) & 127, hl = (pidx >> 10) & 1, kk = (pidx >> 11) & 1;
    int tile = pidx >> 12;
    int mt = tile / kKTQKV, kt = tile - mt * kKTQKV;
    int m = mt * 128 + row;
    int k = kt * 32 + kk * 16 + hl * 8 + j;
    int srcs = (k >= 2304) ? 1 : 0;
    int r = k - srcs * 2304;
    int tap = r >> 8, ic = r & 255;
    const float* w; int mm;
    if (m < 256)      { w = srcs ? wq_h : wq_x; mm = m; }
    else if (m < 512) { w = srcs ? wk_h : wk_x; mm = m - 256; }
    else              { w = srcs ? wv_h : wv_x; mm = m - 512; }
    dst[pidx] = (_Float16)w[((size_t)mm * 256 + ic) * 9 + tap];
}

// gates pack: M=1024, rows interleaved as (channel,gate) quads.
// P = mt*128+row; m = (P&3)*256 + (P>>5)*8 + ((P>>2)&7). K tail (>=4608) from wg_a.
__global__ void pack_gates_kernel(const float* __restrict__ wg_x, const float* __restrict__ wg_h,
                                  const float* __restrict__ wg_a, _Float16* __restrict__ dst) {
    int pidx = blockIdx.x * 256 + threadIdx.x;
    int j = pidx & 7, row = (pidx >> 3) & 127, hl = (pidx >> 10) & 1, kk = (pidx >> 11) & 1;
    int tile = pidx >> 12;
    int mt = tile / kKTG, kt = tile - mt * kKTG;
    int P = mt * 128 + row;
    int T = P >> 5, ch_local = (P >> 2) & 7, g = P & 3;
    int m = g * 256 + T * 8 + ch_local;
    int k = kt * 32 + kk * 16 + hl * 8 + j;
    float val;
    if (k < 4608) {
        int srcs = (k >= 2304) ? 1 : 0;
        int r = k - srcs * 2304;
        int tap = r >> 8, ic = r & 255;
        const float* w = srcs ? wg_h : wg_x;
        val = w[((size_t)m * 256 + ic) * 9 + tap];
    } else {
        val = wg_a[(size_t)m * 256 + (k - 4608)];
    }
    dst[pidx] = (_Float16)val;
}

// out pack: M=256 (2 mt), K=256, direct [m][k].
__global__ void pack_out_kernel(const float* __restrict__ src, _Float16* __restrict__ dst) {
    int pidx = blockIdx.x * 256 + threadIdx.x;
    int j = pidx & 7, row = (pidx >> 3) & 127, hl = (pidx >> 10) & 1, kk = (pidx >> 11) & 1;
    int tile = pidx >> 12;
    int mt = tile >> 3, kt = tile & 7;
    int m = mt * 128 + row;
    int k = kt * 32 + kk * 16 + hl * 8 + j;
    dst[pidx] = (_Float16)src[(size_t)m * 256 + k];
}

// ---------------- input staging ----------------
// h0 [n][256][576] fp32 -> NHWC fp16 padded [n][26][26][256]
__global__ void pad_nhwc_kernel(const float* __restrict__ src, _Float16* __restrict__ dst) {
    __shared__ float tile[32][65];
    int pxt = blockIdx.x, ict = blockIdx.y, n = blockIdx.z;
    int tid = threadIdx.x;
    {
        int icl = tid >> 6, pxl = tid & 63;
        #pragma unroll
        for (int rep = 0; rep < 8; ++rep) {
            int ic = ict * 32 + rep * 4 + icl;
            tile[rep * 4 + icl][pxl] = src[((size_t)n * 256 + ic) * kQ + pxt * 64 + pxl];
        }
    }
    __syncthreads();
    {
        int icl = tid & 31, pxl0 = tid >> 5;
        #pragma unroll
        for (int rep = 0; rep < 8; ++rep) {
            int pxl = rep * 8 + pxl0;
            int px = pxt * 64 + pxl;
            int y = px / kHW, x = px - y * kHW;
            dst[((size_t)n * kPP + (size_t)(y + 1) * 26 + (x + 1)) * 256 + ict * 32 + icl] =
                (_Float16)tile[icl][pxl];
        }
    }
}

// xin = 1x1 conv(x, w_in)+b_in -> NHWC fp16 padded
__global__ void conv1x1_pad_kernel(const float* __restrict__ x, const float* __restrict__ w,
                                   const float* __restrict__ b, _Float16* __restrict__ out) {
    int px = blockIdx.x * 64 + threadIdx.x;
    int n = blockIdx.z;
    int oc0 = __builtin_amdgcn_readfirstlane(blockIdx.y * 16 + threadIdx.y * 4);
    const float* ip = x + (size_t)n * kI * kQ + px;
    float acc[4] = {0.f, 0.f, 0.f, 0.f};
    #pragma unroll 4
    for (int ic = 0; ic < kI; ++ic) {
        float xv = ip[(size_t)ic * kQ];
        #pragma unroll
        for (int j = 0; j < 4; ++j) acc[j] = fmaf(xv, w[(size_t)(oc0 + j) * kI + ic], acc[j]);
    }
    int y = px / kHW, xc = px - y * kHW;
    _Float16* op = out + ((size_t)n * kPP + (size_t)(y + 1) * 26 + (xc + 1)) * 256 + oc0;
    #pragma unroll
    for (int j = 0; j < 4; ++j) op[j] = (_Float16)(acc[j] + b[oc0 + j]);
}

// ---------------- fused MFMA GEMM (pipelined, high-occupancy) ----------------
// Block 256 thr = 4 waves; block tile 128 rows x 64 px; wave = 32 rows x 64 px
// (4 mfma per kt per wave). A: direct global frag loads, distance-2 prefetch.
// B: half8/thread -> pitch-40 LDS, double-buffered, ONE barrier per kt:
//   read Bs[slot] -> prefetch(kt+2) -> mfma -> store B(kt+1) into other slot -> barrier.
// BMODE 0: im2col from two NHWC images | 1: direct [n][576][Ktot] | 2: im2col + a16 tail
// EMODE 0: mt 0-1 -> q16c, 2-3 -> kT16, 4-5 -> vC16(+bias)
// EMODE 3: gates + in-register LSTM -> h16 | EMODE 2: out = acc + bias -> outf
template<int BMODE, int EMODE>
__global__ __launch_bounds__(256)
void gemm_kernel(const _Float16* __restrict__ Apack,
                 const _Float16* __restrict__ B1, const _Float16* __restrict__ B2,
                 const _Float16* __restrict__ B3,
                 _Float16* __restrict__ q16, _Float16* __restrict__ k16,
                 _Float16* __restrict__ v16, _Float16* __restrict__ h16,
                 const float* __restrict__ c0, float* __restrict__ outf,
                 const float* __restrict__ bias, int Ktiles, int Ktot) {
    __shared__ _Float16 Bs[2][2560];     // 64 px * 40 halves, double-buffered
    const int tid = threadIdx.x;
    const int wv = tid >> 6, lane = tid & 63, l31 = lane & 31, hl = lane >> 5;
    const int nt = blockIdx.x, mt = blockIdx.y, n = blockIdx.z;

    floatx16 acc0 = {}, acc1 = {};

    const _Float16* abase = Apack + (size_t)mt * Ktiles * 4096
                          + hl * 1024 + (size_t)(wv * 32 + l31) * 8;
    // A frag: + kk*2048 ; per kt advance 4096

    const int px_l = tid >> 2, bc = tid & 3;
    const int px = nt * 64 + px_l;
    const int by = px / kHW, bx = px - by * kHW;
    const int wofs = px_l * 40 + bc * 8;
    const int r0 = l31 * 40 + hl * 8;    // + ntile*1280 + kk*16

    auto bptr = [&](int kt) -> const _Float16* {
        if (BMODE == 2 && kt >= 144)
            return B3 + ((size_t)n * kQ + px) * 256 + (kt - 144) * 32 + bc * 8;
        if (BMODE == 0 || BMODE == 2) {
            int srcs = (kt >= 72) ? 1 : 0;
            int t2 = kt - srcs * 72;
            int tap = t2 >> 3, ict = t2 & 7;
            int ty = (tap * 11) >> 5;          // tap/3 for 0..8
            int tx = tap - ty * 3;
            const _Float16* img = srcs ? B2 : B1;
            return img + ((size_t)n * kPP + (size_t)(by + ty) * 26 + (bx + tx)) * 256
                       + ict * 32 + bc * 8;
        }
        return B1 + ((size_t)n * kQ + px) * Ktot + kt * 32 + bc * 8;
    };

    // prefetch queues (slot = kt&1)
    half8 bq0 = LD8(bptr(0));
    half8 bq1 = LD8(bptr(1));
    half8 aq0[2], aq1[2];
    aq0[0] = LD8(abase);          aq0[1] = LD8(abase + 2048);
    aq1[0] = LD8(abase + 4096);   aq1[1] = LD8(abase + 4096 + 2048);
    ST8(&Bs[0][wofs], bq0);
    __syncthreads();

    for (int kt = 0; kt < Ktiles; kt += 2) {
        // ---- even half (slot 0) ----
        {
            const _Float16* bb = Bs[0];
            half8 b00 = LD8(bb + r0);          // ntile0 kk0
            half8 b01 = LD8(bb + r0 + 1280);   // ntile1 kk0
            half8 b10 = LD8(bb + r0 + 16);     // ntile0 kk1
            half8 b11 = LD8(bb + r0 + 1296);   // ntile1 kk1
            half8 a0 = aq0[0], a1 = aq0[1];
            if (kt + 2 < Ktiles) {
                bq0 = LD8(bptr(kt + 2));
                const _Float16* ap = abase + (size_t)(kt + 2) * 4096;
                aq0[0] = LD8(ap);  aq0[1] = LD8(ap + 2048);
            }
            acc0 = __builtin_amdgcn_mfma_f32_32x32x16_f16(a0, b00, acc0, 0, 0, 0);
            acc1 = __builtin_amdgcn_mfma_f32_32x32x16_f16(a0, b01, acc1, 0, 0, 0);
            acc0 = __builtin_amdgcn_mfma_f32_32x32x16_f16(a1, b10, acc0, 0, 0, 0);
            acc1 = __builtin_amdgcn_mfma_f32_32x32x16_f16(a1, b11, acc1, 0, 0, 0);
            ST8(&Bs[1][wofs], bq1);            // B(kt+1), loaded 2 halves ago
            __syncthreads();
        }
        // ---- odd half (slot 1) ----
        {
            const _Float16* bb = Bs[1];
            half8 b00 = LD8(bb + r0);
            half8 b01 = LD8(bb + r0 + 1280);
            half8 b10 = LD8(bb + r0 + 16);
            half8 b11 = LD8(bb + r0 + 1296);
            half8 a0 = aq1[0], a1 = aq1[1];
            if (kt + 3 < Ktiles) {
                bq1 = LD8(bptr(kt + 3));
                const _Float16* ap = abase + (size_t)(kt + 3) * 4096;
                aq1[0] = LD8(ap);  aq1[1] = LD8(ap + 2048);
            }
            acc0 = __builtin_amdgcn_mfma_f32_32x32x16_f16(a0, b00, acc0, 0, 0, 0);
            acc1 = __builtin_amdgcn_mfma_f32_32x32x16_f16(a0, b01, acc1, 0, 0, 0);
            acc0 = __builtin_amdgcn_mfma_f32_32x32x16_f16(a1, b10, acc0, 0, 0, 0);
            acc1 = __builtin_amdgcn_mfma_f32_32x32x16_f16(a1, b11, acc1, 0, 0, 0);
            if (kt + 2 < Ktiles) ST8(&Bs[0][wofs], bq0);   // B(kt+2)
            __syncthreads();
        }
    }

    // epilogue: C/D layout col=lane&31, row=(r&3)+8*(r>>2)+4*hl
    #pragma unroll
    for (int ntile = 0; ntile < 2; ++ntile) {
        const floatx16& A = ntile ? acc1 : acc0;
        const int pxe = nt * 64 + ntile * 32 + l31;
        if (EMODE == 0) {
            const int mrow = mt * 128 + wv * 32;
            if (mrow < 256) {
                #pragma unroll
                for (int r = 0; r < 16; ++r) {
                    int rowi = (r & 3) + 8 * (r >> 2) + 4 * hl;
                    q16[((size_t)n * 256 + mrow + rowi) * kQ + pxe] = (_Float16)A[r];
                }
            } else {
                int yy = pxe / kHW, xx = pxe - yy * kHW;
                if (yy >= 1 && yy <= 22 && xx >= 1 && xx <= 22) {
                    int d = (yy - 1) * 22 + (xx - 1);
                    #pragma unroll
                    for (int r = 0; r < 16; ++r) {
                        int ch = (mrow & 255) + (r & 3) + 8 * (r >> 2) + 4 * hl;
                        int head = n * 8 + (ch >> 5);
                        if (mrow < 512)
                            k16[((size_t)head * kDP + d) * 32 + (ch & 31)] = (_Float16)A[r];
                        else
                            v16[((size_t)head * 32 + (ch & 31)) * kDP + d] =
                                (_Float16)(A[r] + bias[ch]);
                    }
                }
            }
        } else if (EMODE == 3) {
            const int T = mt * 4 + wv;
            #pragma unroll
            for (int q4 = 0; q4 < 4; ++q4) {
                int c = T * 8 + 2 * q4 + hl;
                float iv = A[4 * q4 + 0] + bias[c];
                float fv = A[4 * q4 + 1] + bias[256 + c];
                float gv = A[4 * q4 + 2] + bias[512 + c];
                float ov = A[4 * q4 + 3] + bias[768 + c];
                float c0v = c0[((size_t)n * 256 + c) * kQ + pxe];
                float cn = sigm(fv) * c0v + sigm(iv) * tanh_f(gv);
                h16[((size_t)n * kQ + pxe) * 256 + c] = (_Float16)(sigm(ov) * tanh_f(cn));
            }
        } else {
            const int mrow = mt * 128 + wv * 32;
            #pragma unroll
            for (int r = 0; r < 16; ++r) {
                int m = mrow + (r & 3) + 8 * (r >> 2) + 4 * hl;
                outf[((size_t)n * 256 + m) * kQ + pxe] = A[r] + bias[m];
            }
        }
    }
}

// ---------------- MFMA flash attention ----------------
__global__ __launch_bounds__(128)
void attn_kernel(const _Float16* __restrict__ q16c, const _Float16* __restrict__ kT16,
                 const _Float16* __restrict__ vC16, _Float16* __restrict__ a16) {
    const int lane = threadIdx.x & 63;
    const int wv   = threadIdx.x >> 6;
    const int l31 = lane & 31, hl = lane >> 5;
    const int head = blockIdx.y;            // n*8 + hd
    const int n = head >> 3, hd = head & 7;
    const int qt = blockIdx.x * 2 + wv;     // 0..17
    const int q0 = qt * 32;

    half8 qf0, qf1;
    {
        const _Float16* qb = q16c + ((size_t)n * 256 + hd * 32 + hl * 8) * kQ + q0 + l31;
        #pragma unroll
        for (int j = 0; j < 8; ++j) {
            qf0[j] = qb[(size_t)j * kQ];
            qf1[j] = qb[(size_t)(16 + j) * kQ];
        }
    }

    const _Float16* kbase0 = kT16 + ((size_t)head * kDP + l31) * 32 + hl * 8;
    const _Float16* vbase0 = vC16 + ((size_t)head * 32 + l31) * kDP + hl * 8;

    floatx16 acc = {};
    float m_run = -1e30f, l_run = 0.f;

    half8 kf0 = LD8(kbase0);
    half8 kf1 = LD8(kbase0 + 16);

    for (int dt = 0; dt < 16; ++dt) {
        const int d0 = dt * 32;
        floatx16 S = {};
        S = __builtin_amdgcn_mfma_f32_32x32x16_f16(kf0, qf0, S, 0, 0, 0);
        S = __builtin_amdgcn_mfma_f32_32x32x16_f16(kf1, qf1, S, 0, 0, 0);

        half8 vf0 = LD8(vbase0 + d0);
        half8 vf1 = LD8(vbase0 + d0 + 16);
        if (dt < 15) {
            kf0 = LD8(kbase0 + (size_t)(d0 + 32) * 32);
            kf1 = LD8(kbase0 + (size_t)(d0 + 32) * 32 + 16);
        }

        if (dt == 15) {
            #pragma unroll
            for (int r = 0; r < 16; ++r)
                if (!(hl == 0 && r < 4)) S[r] = -1e30f;
        }

        float tmax = S[0];
        #pragma unroll
        for (int r = 1; r < 16; ++r) tmax = fmaxf(tmax, S[r]);
        tmax = fmaxf(tmax, __shfl_xor(tmax, 32));
        float mnew = fmaxf(m_run, tmax);
        float f = __expf(m_run - mnew);
        float p[16], psum = 0.f;
        #pragma unroll
        for (int r = 0; r < 16; ++r) { p[r] = __expf(S[r] - mnew); psum += p[r]; }
        psum += __shfl_xor(psum, 32);
        l_run = f * l_run + psum;
        #pragma unroll
        for (int r = 0; r < 16; ++r) acc[r] *= f;
        m_run = mnew;

        float other[16];
        #pragma unroll
        for (int r = 0; r < 16; ++r) other[r] = __shfl_xor(p[r], 32);
        half8 pf0, pf1;
        #pragma unroll
        for (int t = 0; t < 4; ++t) {
            pf0[t]     = (_Float16)(hl ? other[4 + t]  : p[t]);
            pf0[4 + t] = (_Float16)(hl ? p[4 + t]      : other[t]);
            pf1[t]     = (_Float16)(hl ? other[12 + t] : p[8 + t]);
            pf1[4 + t] = (_Float16)(hl ? p[12 + t]     : other[8 + t]);
        }

        acc = __builtin_amdgcn_mfma_f32_32x32x16_f16(vf0, pf0, acc, 0, 0, 0);
        acc = __builtin_amdgcn_mfma_f32_32x32x16_f16(vf1, pf1, acc, 0, 0, 0);
    }

    float inv = 1.f / l_run;
    _Float16* ap = a16 + ((size_t)n * kQ + q0 + l31) * 256 + hd * 32;
    #pragma unroll
    for (int r = 0; r < 16; ++r) {
        int c = (r & 3) + 8 * (r >> 2) + 4 * hl;
        ap[c] = (_Float16)(acc[r] * inv);
    }
}

extern "C" void kernel_launch(void* const* d_in, const int* in_sizes, int n_in,
                              void* d_out, int out_size, void* d_ws, size_t ws_size,
                              hipStream_t stream) {
    (void)in_sizes; (void)n_in; (void)out_size; (void)ws_size;
    const float* x     = (const float*)d_in[0];
    const float* h0    = (const float*)d_in[1];
    const float* c0    = (const float*)d_in[2];
    const float* w_in  = (const float*)d_in[3];
    const float* b_in  = (const float*)d_in[4];
    const float* wq_x  = (const float*)d_in[5];
    const float* wq_h  = (const float*)d_in[6];
    const float* wk_x  = (const float*)d_in[7];
    const float* wk_h  = (const float*)d_in[8];
    const float* wv_x  = (const float*)d_in[9];
    const float* wv_h  = (const float*)d_in[10];
    const float* bv    = (const float*)d_in[11];
    const float* wg_a  = (const float*)d_in[12];
    const float* bg    = (const float*)d_in[13];
    const float* wg_x  = (const float*)d_in[14];
    const float* wg_h  = (const float*)d_in[15];
    const float* w_out = (const float*)d_in[16];
    const float* b_out = (const float*)d_in[17];

    _Float16* wh = (_Float16*)d_ws;
    _Float16* xpad16  = wh + H_XPAD;
    _Float16* hpad16  = wh + H_HPAD;
    _Float16* apqkv   = wh + H_APQKV;
    _Float16* apg     = wh + H_APG;
    _Float16* apo     = wh + H_APO;
    _Float16* a16     = wh + H_A16;
    _Float16* h16     = wh + H_H16;
    _Float16* q16c    = wh + H_Q16C;
    _Float16* kT16    = wh + H_KT16;
    _Float16* vC16    = wh + H_VC16;

    // zero NHWC image borders (ws re-poisoned each launch)
    hipMemsetAsync(wh, 0, 11075584, stream);

    // weight packing (fragment-order, 128-row tiles)
    pack_qkv_kernel<<<13824, 256, 0, stream>>>(wq_x, wq_h, wk_x, wk_h, wv_x, wv_h, apqkv);
    pack_gates_kernel<<<19456, 256, 0, stream>>>(wg_x, wg_h, wg_a, apg);
    pack_out_kernel<<<256, 256, 0, stream>>>(w_out, apo);

    // input staging (NHWC fp16)
    pad_nhwc_kernel<<<dim3(9, 8, kN), 256, 0, stream>>>(h0, hpad16);
    conv1x1_pad_kernel<<<dim3(9, 16, kN), dim3(64, 4), 0, stream>>>(x, w_in, b_in, xpad16);

    // qkv GEMM: M=768, K=4608, N=576 x16  (864 blocks)
    gemm_kernel<0, 0><<<dim3(9, 6, kN), 256, 0, stream>>>(
        apqkv, xpad16, hpad16, nullptr, q16c, kT16, vC16, nullptr,
        nullptr, nullptr, bv, kKTQKV, 0);

    // MFMA flash attention -> a16 [n][px][256]
    attn_kernel<<<dim3(9, 128), 128, 0, stream>>>(q16c, kT16, vC16, a16);

    // gates GEMM (K=4864: im2col + a16) + fused LSTM -> h16  (1152 blocks)
    gemm_kernel<2, 3><<<dim3(9, 8, kN), 256, 0, stream>>>(
        apg, xpad16, hpad16, a16, nullptr, nullptr, nullptr, h16,
        c0, nullptr, bg, kKTG, 0);

    // out = w_out . h + b_out  (288 blocks)
    gemm_kernel<1, 2><<<dim3(9, 2, kN), 256, 0, stream>>>(
        apo, h16, nullptr, nullptr, nullptr, nullptr, nullptr, nullptr,
        nullptr, (float*)d_out, b_out, kKTO, 256);
}

// Round 9
// 473.468 us; speedup vs baseline: 1.0555x; 1.0555x over previous
//
#include <hip/hip_runtime.h>
#include <cstddef>

// ---- problem constants ----
constexpr int kN  = 16;
constexpr int kI  = 128;
constexpr int kHW = 24;
constexpr int kQ  = 576;    // 24*24
constexpr int kD  = 484;    // 22*22
constexpr int kDP = 512;    // padded d
constexpr int kPP = 676;    // 26*26 padded

// K-tiling
constexpr int kKTQKV = 144;   // K = 4608 (2 src * 9 tap * 256 ic)
constexpr int kKTG   = 152;   // K = 4864 (4608 + 256 from a16)
constexpr int kKTO   = 8;     // K = 256

// ---- workspace layout (element offsets into _Float16*) ----
constexpr size_t H_XPAD   = 0;                          // [16][26][26][256] NHWC
constexpr size_t H_HPAD   = 2768896;                    // [16][26][26][256] NHWC
constexpr size_t H_APQKV  = 5537792;                    // 6 mt * 144 kt * 4096
constexpr size_t H_APG    = 9076736;                    // 8 mt * 152 kt * 4096
constexpr size_t H_APO    = 14057472;                   // 2 mt * 8 kt * 4096
constexpr size_t H_A16    = 14123008;                   // [16][576][256]
constexpr size_t H_H16    = 16482304;                   // [16][576][256]
constexpr size_t H_Q16C   = 18841600;                   // [16][256][576]
constexpr size_t H_KT16   = 21200896;                   // [128 head][512 d][32 c]
constexpr size_t H_VC16   = 23298048;                   // [128 head][32 c][512 d]

using half8    = __attribute__((ext_vector_type(8))) _Float16;
using floatx16 = __attribute__((ext_vector_type(16))) float;

__device__ __forceinline__ float sigm(float x) { return 1.0f / (1.0f + __expf(-x)); }
__device__ __forceinline__ float tanh_f(float x) {
    float e = __expf(2.0f * fabsf(x));
    float r = 1.0f - 2.0f / (e + 1.0f);
    return copysignf(r, x);
}
__device__ __forceinline__ half8 LD8(const _Float16* p) { return *(const half8*)p; }
__device__ __forceinline__ void ST8(_Float16* p, half8 v) { *(half8*)p = v; }

// async global->LDS DMA, 16 B per lane; LDS dest = wave-uniform base + lane*16
__device__ __forceinline__ void glds16(const _Float16* g, _Float16* l) {
    __builtin_amdgcn_global_load_lds(
        (const __attribute__((address_space(1))) void*)g,
        (__attribute__((address_space(3))) void*)l, 16, 0, 0);
}

// ---------------- weight packing ----------------
// Apack layout: [mt][kt][kk(2)][hl(2)][row(128)][j(8)], 4096 halves per (mt,kt).
// K-order (im2col GEMMs): k = src*2304 + tap*256 + ic.

// qkv pack: M=768 (mt 0-1 q, 2-3 k, 4-5 v).
__global__ void pack_qkv_kernel(const float* __restrict__ wq_x, const float* __restrict__ wq_h,
                                const float* __restrict__ wk_x, const float* __restrict__ wk_h,
                                const float* __restrict__ wv_x, const float* __restrict__ wv_h,
                                _Float16* __restrict__ dst) {
    int pidx = blockIdx.x * 256 + threadIdx.x;
    int j = pidx & 7, row = (pidx >> 3) & 127, hl = (pidx >> 10) & 1, kk = (pidx >> 11) & 1;
    int tile = pidx >> 12;
    int mt = tile / kKTQKV, kt = tile - mt * kKTQKV;
    int m = mt * 128 + row;
    int k = kt * 32 + kk * 16 + hl * 8 + j;
    int srcs = (k >= 2304) ? 1 : 0;
    int r = k - srcs * 2304;
    int tap = r >> 8, ic = r & 255;
    const float* w; int mm;
    if (m < 256)      { w = srcs ? wq_h : wq_x; mm = m; }
    else if (m < 512) { w = srcs ? wk_h : wk_x; mm = m - 256; }
    else              { w = srcs ? wv_h : wv_x; mm = m - 512; }
    dst[pidx] = (_Float16)w[((size_t)mm * 256 + ic) * 9 + tap];
}

// gates pack: M=1024, rows interleaved as (channel,gate) quads.
// P = mt*128+row; m = (P&3)*256 + (P>>5)*8 + ((P>>2)&7). K tail (>=4608) from wg_a.
__global__ void pack_gates_kernel(const float* __restrict__ wg_x, const float* __restrict__ wg_h,
                                  const float* __restrict__ wg_a, _Float16* __restrict__ dst) {
    int pidx = blockIdx.x * 256 + threadIdx.x;
    int j = pidx & 7, row = (pidx >> 3) & 127, hl = (pidx >> 10) & 1, kk = (pidx >> 11) & 1;
    int tile = pidx >> 12;
    int mt = tile / kKTG, kt = tile - mt * kKTG;
    int P = mt * 128 + row;
    int T = P >> 5, ch_local = (P >> 2) & 7, g = P & 3;
    int m = g * 256 + T * 8 + ch_local;
    int k = kt * 32 + kk * 16 + hl * 8 + j;
    float val;
    if (k < 4608) {
        int srcs = (k >= 2304) ? 1 : 0;
        int r = k - srcs * 2304;
        int tap = r >> 8, ic = r & 255;
        const float* w = srcs ? wg_h : wg_x;
        val = w[((size_t)m * 256 + ic) * 9 + tap];
    } else {
        val = wg_a[(size_t)m * 256 + (k - 4608)];
    }
    dst[pidx] = (_Float16)val;
}

// out pack: M=256 (2 mt), K=256, direct [m][k].
__global__ void pack_out_kernel(const float* __restrict__ src, _Float16* __restrict__ dst) {
    int pidx = blockIdx.x * 256 + threadIdx.x;
    int j = pidx & 7, row = (pidx >> 3) & 127, hl = (pidx >> 10) & 1, kk = (pidx >> 11) & 1;
    int tile = pidx >> 12;
    int mt = tile >> 3, kt = tile & 7;
    int m = mt * 128 + row;
    int k = kt * 32 + kk * 16 + hl * 8 + j;
    dst[pidx] = (_Float16)src[(size_t)m * 256 + k];
}

// ---------------- input staging ----------------
// h0 [n][256][576] fp32 -> NHWC fp16 padded [n][26][26][256]
__global__ void pad_nhwc_kernel(const float* __restrict__ src, _Float16* __restrict__ dst) {
    __shared__ float tile[32][65];
    int pxt = blockIdx.x, ict = blockIdx.y, n = blockIdx.z;
    int tid = threadIdx.x;
    {
        int icl = tid >> 6, pxl = tid & 63;
        #pragma unroll
        for (int rep = 0; rep < 8; ++rep) {
            int ic = ict * 32 + rep * 4 + icl;
            tile[rep * 4 + icl][pxl] = src[((size_t)n * 256 + ic) * kQ + pxt * 64 + pxl];
        }
    }
    __syncthreads();
    {
        int icl = tid & 31, pxl0 = tid >> 5;
        #pragma unroll
        for (int rep = 0; rep < 8; ++rep) {
            int pxl = rep * 8 + pxl0;
            int px = pxt * 64 + pxl;
            int y = px / kHW, x = px - y * kHW;
            dst[((size_t)n * kPP + (size_t)(y + 1) * 26 + (x + 1)) * 256 + ict * 32 + icl] =
                (_Float16)tile[icl][pxl];
        }
    }
}

// xin = 1x1 conv(x, w_in)+b_in -> NHWC fp16 padded
__global__ void conv1x1_pad_kernel(const float* __restrict__ x, const float* __restrict__ w,
                                   const float* __restrict__ b, _Float16* __restrict__ out) {
    int px = blockIdx.x * 64 + threadIdx.x;
    int n = blockIdx.z;
    int oc0 = __builtin_amdgcn_readfirstlane(blockIdx.y * 16 + threadIdx.y * 4);
    const float* ip = x + (size_t)n * kI * kQ + px;
    float acc[4] = {0.f, 0.f, 0.f, 0.f};
    #pragma unroll 4
    for (int ic = 0; ic < kI; ++ic) {
        float xv = ip[(size_t)ic * kQ];
        #pragma unroll
        for (int j = 0; j < 4; ++j) acc[j] = fmaf(xv, w[(size_t)(oc0 + j) * kI + ic], acc[j]);
    }
    int y = px / kHW, xc = px - y * kHW;
    _Float16* op = out + ((size_t)n * kPP + (size_t)(y + 1) * 26 + (xc + 1)) * 256 + oc0;
    #pragma unroll
    for (int j = 0; j < 4; ++j) op[j] = (_Float16)(acc[j] + b[oc0 + j]);
}

// ---------------- fused MFMA GEMM (async-DMA, BK=64 per barrier) ----------------
// Block 256 thr = 4 waves; block tile 128 rows x 64 px; wave = 32 rows x 64 px.
// Grid: x = n*9 + nt (144), y = mt  => co-resident blocks share one mt (A fits XCD L2).
// B: global_load_lds (16 B/lane DMA, per-lane gather addr, wave-uniform LDS base),
//    2 kt per buffer, double-buffered, ONE barrier per 2-kt step (8 mfma/step).
// A: direct global fragment loads, next-step register prefetch.
// BMODE 0: im2col from two NHWC images | 1: direct [n][576][Ktot] | 2: im2col + a16 tail
// EMODE 0: mt 0-1 -> q16c, 2-3 -> kT16, 4-5 -> vC16(+bias)
// EMODE 3: gates + in-register LSTM -> h16 | EMODE 2: out = acc + bias -> outf
template<int BMODE, int EMODE>
__global__ __launch_bounds__(256)
void gemm_kernel(const _Float16* __restrict__ Apack,
                 const _Float16* __restrict__ B1, const _Float16* __restrict__ B2,
                 const _Float16* __restrict__ B3,
                 _Float16* __restrict__ q16, _Float16* __restrict__ k16,
                 _Float16* __restrict__ v16, _Float16* __restrict__ h16,
                 const float* __restrict__ c0, float* __restrict__ outf,
                 const float* __restrict__ bias, int Ktiles, int Ktot) {
    __shared__ _Float16 Bs[2][4096];   // buf: [sub(2)][px(64)][k(32)]
    const int tid = threadIdx.x;
    const int wv = tid >> 6, lane = tid & 63, l31 = lane & 31, hl = lane >> 5;
    const int bxid = blockIdx.x;
    const int n = bxid / 9, nt = bxid - n * 9;
    const int mt = blockIdx.y;

    floatx16 acc0 = {}, acc1 = {};

    const _Float16* abase = Apack + (size_t)mt * Ktiles * 4096
                          + hl * 1024 + (size_t)(wv * 32 + l31) * 8;

    // DMA source mapping: lane covers px_l = wv*16 + (lane>>2), k-chunk bc = lane&3
    const int px_l = wv * 16 + (lane >> 2);
    const int bc = lane & 3;
    const int px = nt * 64 + px_l;
    const int by = px / kHW, bxp = px - by * kHW;
    // wave-uniform LDS base (halves) for sub s: s*2048 + wv*512
    _Float16* ldsw0 = &Bs[0][wv * 512];
    _Float16* ldsw1 = &Bs[1][wv * 512];

    auto gaddr = [&](int kt) -> const _Float16* {
        if (BMODE == 2 && kt >= 144)
            return B3 + ((size_t)n * kQ + px) * 256 + (kt - 144) * 32 + bc * 8;
        if (BMODE == 0 || BMODE == 2) {
            int srcs = (kt >= 72) ? 1 : 0;
            int t2 = kt - srcs * 72;
            int tap = t2 >> 3, ict = t2 & 7;
            int ty = (tap * 11) >> 5;          // tap/3 for 0..8
            int tx = tap - ty * 3;
            const _Float16* img = srcs ? B2 : B1;
            return img + ((size_t)n * kPP + (size_t)(by + ty) * 26 + (bxp + tx)) * 256
                       + ict * 32 + bc * 8;
        }
        return B1 + ((size_t)n * kQ + px) * Ktot + kt * 32 + bc * 8;
    };

    const int steps = Ktiles >> 1;

    // prologue: DMA step 0 into buf 0; A frags for step 0
    glds16(gaddr(0), ldsw0);
    glds16(gaddr(1), ldsw0 + 2048);
    half8 aq0 = LD8(abase);
    half8 aq1 = LD8(abase + 2048);
    half8 aq2 = LD8(abase + 4096);
    half8 aq3 = LD8(abase + 4096 + 2048);
    __syncthreads();

    for (int s = 0; s < steps; ++s) {
        const int buf = s & 1;
        // issue DMA for step s+1 into the other buffer (overlaps this step's compute)
        if (s + 1 < steps) {
            _Float16* ld = buf ? ldsw0 : ldsw1;
            glds16(gaddr(2 * s + 2), ld);
            glds16(gaddr(2 * s + 3), ld + 2048);
        }
        half8 a0 = aq0, a1 = aq1, a2 = aq2, a3 = aq3;
        if (s + 1 < steps) {
            const _Float16* ap = abase + (size_t)(2 * s + 2) * 4096;
            aq0 = LD8(ap);          aq1 = LD8(ap + 2048);
            aq2 = LD8(ap + 4096);   aq3 = LD8(ap + 4096 + 2048);
        }
        const _Float16* bb = Bs[buf];
        const int r0 = l31 * 32 + hl * 8;
        // sub 0 (kt = 2s)
        half8 b00 = LD8(bb + r0);            // ntile0 kk0
        half8 b01 = LD8(bb + r0 + 1024);     // ntile1 kk0
        half8 b10 = LD8(bb + r0 + 16);       // ntile0 kk1
        half8 b11 = LD8(bb + r0 + 1040);     // ntile1 kk1
        acc0 = __builtin_amdgcn_mfma_f32_32x32x16_f16(a0, b00, acc0, 0, 0, 0);
        acc1 = __builtin_amdgcn_mfma_f32_32x32x16_f16(a0, b01, acc1, 0, 0, 0);
        acc0 = __builtin_amdgcn_mfma_f32_32x32x16_f16(a1, b10, acc0, 0, 0, 0);
        acc1 = __builtin_amdgcn_mfma_f32_32x32x16_f16(a1, b11, acc1, 0, 0, 0);
        // sub 1 (kt = 2s+1)
        half8 c00 = LD8(bb + 2048 + r0);
        half8 c01 = LD8(bb + 2048 + r0 + 1024);
        half8 c10 = LD8(bb + 2048 + r0 + 16);
        half8 c11 = LD8(bb + 2048 + r0 + 1040);
        acc0 = __builtin_amdgcn_mfma_f32_32x32x16_f16(a2, c00, acc0, 0, 0, 0);
        acc1 = __builtin_amdgcn_mfma_f32_32x32x16_f16(a2, c01, acc1, 0, 0, 0);
        acc0 = __builtin_amdgcn_mfma_f32_32x32x16_f16(a3, c10, acc0, 0, 0, 0);
        acc1 = __builtin_amdgcn_mfma_f32_32x32x16_f16(a3, c11, acc1, 0, 0, 0);
        __syncthreads();   // drains DMA(s+1) + aligns buffer reuse
    }

    // epilogue: C/D layout col=lane&31, row=(r&3)+8*(r>>2)+4*hl
    #pragma unroll
    for (int ntile = 0; ntile < 2; ++ntile) {
        const floatx16& A = ntile ? acc1 : acc0;
        const int pxe = nt * 64 + ntile * 32 + l31;
        if (EMODE == 0) {
            const int mrow = mt * 128 + wv * 32;
            if (mrow < 256) {
                #pragma unroll
                for (int r = 0; r < 16; ++r) {
                    int rowi = (r & 3) + 8 * (r >> 2) + 4 * hl;
                    q16[((size_t)n * 256 + mrow + rowi) * kQ + pxe] = (_Float16)A[r];
                }
            } else {
                int yy = pxe / kHW, xx = pxe - yy * kHW;
                if (yy >= 1 && yy <= 22 && xx >= 1 && xx <= 22) {
                    int d = (yy - 1) * 22 + (xx - 1);
                    #pragma unroll
                    for (int r = 0; r < 16; ++r) {
                        int ch = (mrow & 255) + (r & 3) + 8 * (r >> 2) + 4 * hl;
                        int head = n * 8 + (ch >> 5);
                        if (mrow < 512)
                            k16[((size_t)head * kDP + d) * 32 + (ch & 31)] = (_Float16)A[r];
                        else
                            v16[((size_t)head * 32 + (ch & 31)) * kDP + d] =
                                (_Float16)(A[r] + bias[ch]);
                    }
                }
            }
        } else if (EMODE == 3) {
            const int T = mt * 4 + wv;
            #pragma unroll
            for (int q4 = 0; q4 < 4; ++q4) {
                int c = T * 8 + 2 * q4 + hl;
                float iv = A[4 * q4 + 0] + bias[c];
                float fv = A[4 * q4 + 1] + bias[256 + c];
                float gv = A[4 * q4 + 2] + bias[512 + c];
                float ov = A[4 * q4 + 3] + bias[768 + c];
                float c0v = c0[((size_t)n * 256 + c) * kQ + pxe];
                float cn = sigm(fv) * c0v + sigm(iv) * tanh_f(gv);
                h16[((size_t)n * kQ + pxe) * 256 + c] = (_Float16)(sigm(ov) * tanh_f(cn));
            }
        } else {
            const int mrow = mt * 128 + wv * 32;
            #pragma unroll
            for (int r = 0; r < 16; ++r) {
                int m = mrow + (r & 3) + 8 * (r >> 2) + 4 * hl;
                outf[((size_t)n * 256 + m) * kQ + pxe] = A[r] + bias[m];
            }
        }
    }
}

// ---------------- MFMA flash attention ----------------
__global__ __launch_bounds__(128)
void attn_kernel(const _Float16* __restrict__ q16c, const _Float16* __restrict__ kT16,
                 const _Float16* __restrict__ vC16, _Float16* __restrict__ a16) {
    const int lane = threadIdx.x & 63;
    const int wv   = threadIdx.x >> 6;
    const int l31 = lane & 31, hl = lane >> 5;
    const int head = blockIdx.y;            // n*8 + hd
    const int n = head >> 3, hd = head & 7;
    const int qt = blockIdx.x * 2 + wv;     // 0..17
    const int q0 = qt * 32;

    half8 qf0, qf1;
    {
        const _Float16* qb = q16c + ((size_t)n * 256 + hd * 32 + hl * 8) * kQ + q0 + l31;
        #pragma unroll
        for (int j = 0; j < 8; ++j) {
            qf0[j] = qb[(size_t)j * kQ];
            qf1[j] = qb[(size_t)(16 + j) * kQ];
        }
    }

    const _Float16* kbase0 = kT16 + ((size_t)head * kDP + l31) * 32 + hl * 8;
    const _Float16* vbase0 = vC16 + ((size_t)head * 32 + l31) * kDP + hl * 8;

    floatx16 acc = {};
    float m_run = -1e30f, l_run = 0.f;

    half8 kf0 = LD8(kbase0);
    half8 kf1 = LD8(kbase0 + 16);

    for (int dt = 0; dt < 16; ++dt) {
        const int d0 = dt * 32;
        floatx16 S = {};
        S = __builtin_amdgcn_mfma_f32_32x32x16_f16(kf0, qf0, S, 0, 0, 0);
        S = __builtin_amdgcn_mfma_f32_32x32x16_f16(kf1, qf1, S, 0, 0, 0);

        half8 vf0 = LD8(vbase0 + d0);
        half8 vf1 = LD8(vbase0 + d0 + 16);
        if (dt < 15) {
            kf0 = LD8(kbase0 + (size_t)(d0 + 32) * 32);
            kf1 = LD8(kbase0 + (size_t)(d0 + 32) * 32 + 16);
        }

        if (dt == 15) {
            #pragma unroll
            for (int r = 0; r < 16; ++r)
                if (!(hl == 0 && r < 4)) S[r] = -1e30f;
        }

        float tmax = S[0];
        #pragma unroll
        for (int r = 1; r < 16; ++r) tmax = fmaxf(tmax, S[r]);
        tmax = fmaxf(tmax, __shfl_xor(tmax, 32));
        float mnew = fmaxf(m_run, tmax);
        float f = __expf(m_run - mnew);
        float p[16], psum = 0.f;
        #pragma unroll
        for (int r = 0; r < 16; ++r) { p[r] = __expf(S[r] - mnew); psum += p[r]; }
        psum += __shfl_xor(psum, 32);
        l_run = f * l_run + psum;
        #pragma unroll
        for (int r = 0; r < 16; ++r) acc[r] *= f;
        m_run = mnew;

        float other[16];
        #pragma unroll
        for (int r = 0; r < 16; ++r) other[r] = __shfl_xor(p[r], 32);
        half8 pf0, pf1;
        #pragma unroll
        for (int t = 0; t < 4; ++t) {
            pf0[t]     = (_Float16)(hl ? other[4 + t]  : p[t]);
            pf0[4 + t] = (_Float16)(hl ? p[4 + t]      : other[t]);
            pf1[t]     = (_Float16)(hl ? other[12 + t] : p[8 + t]);
            pf1[4 + t] = (_Float16)(hl ? p[12 + t]     : other[8 + t]);
        }

        acc = __builtin_amdgcn_mfma_f32_32x32x16_f16(vf0, pf0, acc, 0, 0, 0);
        acc = __builtin_amdgcn_mfma_f32_32x32x16_f16(vf1, pf1, acc, 0, 0, 0);
    }

    float inv = 1.f / l_run;
    _Float16* ap = a16 + ((size_t)n * kQ + q0 + l31) * 256 + hd * 32;
    #pragma unroll
    for (int r = 0; r < 16; ++r) {
        int c = (r & 3) + 8 * (r >> 2) + 4 * hl;
        ap[c] = (_Float16)(acc[r] * inv);
    }
}

extern "C" void kernel_launch(void* const* d_in, const int* in_sizes, int n_in,
                              void* d_out, int out_size, void* d_ws, size_t ws_size,
                              hipStream_t stream) {
    (void)in_sizes; (void)n_in; (void)out_size; (void)ws_size;
    const float* x     = (const float*)d_in[0];
    const float* h0    = (const float*)d_in[1];
    const float* c0    = (const float*)d_in[2];
    const float* w_in  = (const float*)d_in[3];
    const float* b_in  = (const float*)d_in[4];
    const float* wq_x  = (const float*)d_in[5];
    const float* wq_h  = (const float*)d_in[6];
    const float* wk_x  = (const float*)d_in[7];
    const float* wk_h  = (const float*)d_in[8];
    const float* wv_x  = (const float*)d_in[9];
    const float* wv_h  = (const float*)d_in[10];
    const float* bv    = (const float*)d_in[11];
    const float* wg_a  = (const float*)d_in[12];
    const float* bg    = (const float*)d_in[13];
    const float* wg_x  = (const float*)d_in[14];
    const float* wg_h  = (const float*)d_in[15];
    const float* w_out = (const float*)d_in[16];
    const float* b_out = (const float*)d_in[17];

    _Float16* wh = (_Float16*)d_ws;
    _Float16* xpad16  = wh + H_XPAD;
    _Float16* hpad16  = wh + H_HPAD;
    _Float16* apqkv   = wh + H_APQKV;
    _Float16* apg     = wh + H_APG;
    _Float16* apo     = wh + H_APO;
    _Float16* a16     = wh + H_A16;
    _Float16* h16     = wh + H_H16;
    _Float16* q16c    = wh + H_Q16C;
    _Float16* kT16    = wh + H_KT16;
    _Float16* vC16    = wh + H_VC16;

    // zero NHWC image borders (ws re-poisoned each launch)
    hipMemsetAsync(wh, 0, 11075584, stream);

    // weight packing (fragment-order, 128-row tiles)
    pack_qkv_kernel<<<13824, 256, 0, stream>>>(wq_x, wq_h, wk_x, wk_h, wv_x, wv_h, apqkv);
    pack_gates_kernel<<<19456, 256, 0, stream>>>(wg_x, wg_h, wg_a, apg);
    pack_out_kernel<<<256, 256, 0, stream>>>(w_out, apo);

    // input staging (NHWC fp16)
    pad_nhwc_kernel<<<dim3(9, 8, kN), 256, 0, stream>>>(h0, hpad16);
    conv1x1_pad_kernel<<<dim3(9, 16, kN), dim3(64, 4), 0, stream>>>(x, w_in, b_in, xpad16);

    // qkv GEMM: M=768, K=4608, N=576 x16  (864 blocks; x = n*9+nt, y = mt)
    gemm_kernel<0, 0><<<dim3(144, 6), 256, 0, stream>>>(
        apqkv, xpad16, hpad16, nullptr, q16c, kT16, vC16, nullptr,
        nullptr, nullptr, bv, kKTQKV, 0);

    // MFMA flash attention -> a16 [n][px][256]
    attn_kernel<<<dim3(9, 128), 128, 0, stream>>>(q16c, kT16, vC16, a16);

    // gates GEMM (K=4864: im2col + a16) + fused LSTM -> h16  (1152 blocks)
    gemm_kernel<2, 3><<<dim3(144, 8), 256, 0, stream>>>(
        apg, xpad16, hpad16, a16, nullptr, nullptr, nullptr, h16,
        c0, nullptr, bg, kKTG, 0);

    // out = w_out . h + b_out  (288 blocks)
    gemm_kernel<1, 2><<<dim3(144, 2), 256, 0, stream>>>(
        apo, h16, nullptr, nullptr, nullptr, nullptr, nullptr, nullptr,
        nullptr, (float*)d_out, b_out, kKTO, 256);
}